// Round 7
// baseline (705.527 us; speedup 1.0000x reference)
//
#include <hip/hip_runtime.h>
#include <math.h>

typedef unsigned short u16;
typedef unsigned int u32;
typedef __attribute__((ext_vector_type(8))) short short8;   // 8 bf16 = 4 VGPRs
typedef __attribute__((ext_vector_type(4))) float floatx4;  // MFMA 16x16 accumulator

#define DEVINL static __device__ __forceinline__

// pack 2 fp32 -> 2 bf16 (RNE), src0 -> low half, src1 -> high half
DEVINL u32 pk2(float a, float b) {
  u32 r;
  asm("v_cvt_pk_bf16_f32 %0, %1, %2" : "=v"(r) : "v"(a), "v"(b));
  return r;
}
// raw v_exp_f32: returns 2^x
DEVINL float exp2fast(float x) {
  float r;
  asm("v_exp_f32 %0, %1" : "=v"(r) : "v"(x));
  return r;
}

DEVINL void gload16(const void* g, void* lds_base) {
  __builtin_amdgcn_global_load_lds(
      (const __attribute__((address_space(1))) void*)g,
      (__attribute__((address_space(3))) void*)lds_base, 16, 0, 0);
}

// Stage a 128x64 fp32 A-tile into swizzled bf16 LDS chunks (same layout the
// MFMA fragment reader uses). 8 rounds x 256 threads x float4.
DEVINL void stage_a_f32(const float* __restrict__ A, int lda, int gm0, int k0,
                        u16* As, int tid) {
  const int idx = tid & 127;
  const int row8 = idx >> 4;
  const int k16h = idx & 15;
  const int chsel = tid >> 7;
#pragma unroll
  for (int rr = 0; rr < 8; ++rr) {
    const int chunk = rr * 2 + chsel;
    const float4 v = *(const float4*)(A + (long)(gm0 + chunk * 8 + row8) * lda + k0 + k16h * 4);
    const int baddr = chunk * 1024 + row8 * 128 + (((k16h >> 1) ^ row8) << 4) + ((k16h & 1) << 3);
    uint2 p; p.x = pk2(v.x, v.y); p.y = pk2(v.z, v.w);
    *(uint2*)((char*)As + baddr) = p;
  }
}

// ---------------------------------------------------------------- cast fp32->bf16 (weights only)
__global__ __launch_bounds__(256) void cast4_kernel(const float* __restrict__ in,
                                                    u16* __restrict__ out, long n4) {
  long i = (long)blockIdx.x * blockDim.x + threadIdx.x;
  long stride = (long)gridDim.x * blockDim.x;
  for (; i < n4; i += stride) {
    float4 v = ((const float4*)in)[i];
    uint2 o; o.x = pk2(v.x, v.y); o.y = pk2(v.z, v.w);
    ((uint2*)out)[i] = o;
  }
}

// ---------------------------------------------------------------- zero fp32 buffer
__global__ __launch_bounds__(256) void zerof(float* __restrict__ p, int n4) {
  int i = blockIdx.x * 256 + threadIdx.x;
  if (i < n4) ((float4*)p)[i] = make_float4(0.f, 0.f, 0.f, 0.f);
}

// ---------------------------------------------------------------- Q projection
// Stores Q' = (x Wq^T + bq) * oscale, oscale = softmax_scale * log2(e).
// XCD-clustered: each XCD's contiguous block chunk = 32 m-panels x all 4
// n-blocks, so the shared A-panel (256 KB fp32) is reused within one L2.
__global__ __launch_bounds__(256) void proj_q(const float* __restrict__ A,
                                              const u16* __restrict__ Bt,
                                              const float* __restrict__ bias,
                                              u16* __restrict__ C, float oscale) {
  __shared__ u16 As[8192];
  __shared__ u16 Bs[8192];
  const int tid = threadIdx.x;
  const int lane = tid & 63;
  const int wave = tid >> 6;
  const int orig = blockIdx.y * 4 + blockIdx.x;      // 0..1023, XCD = orig%8
  const int swz = (orig & 7) * 128 + (orig >> 3);    // bijective chunk swizzle
  const int gm0 = (swz >> 2) * 128;                  // m-panel 0..255
  const int gn0 = (swz & 3) * 128;                   // n-block 0..3
  const int wm = (wave >> 1) * 64;
  const int wn = (wave & 1) * 64;

  floatx4 acc[4][4];
#pragma unroll
  for (int i = 0; i < 4; ++i)
#pragma unroll
    for (int j = 0; j < 4; ++j)
#pragma unroll
      for (int r = 0; r < 4; ++r) acc[i][j][r] = 0.0f;

  const int lrow = lane >> 3;
  const int lcol = (lane & 7) ^ lrow;
  const int fr_row = lane & 15;
  const int fr_k16 = lane >> 4;

  for (int k0 = 0; k0 < 512; k0 += 64) {
#pragma unroll
    for (int c = 0; c < 4; ++c) {
      const int ch = wave * 4 + c;
      gload16(Bt + (long)(gn0 + ch * 8 + lrow) * 512 + k0 + lcol * 8, (char*)Bs + ch * 1024);
    }
    stage_a_f32(A, 512, gm0, k0, As, tid);
    __syncthreads();
#pragma unroll
    for (int ks = 0; ks < 2; ++ks) {
      const int c16 = ks * 4 + fr_k16;
      short8 af[4], bfv[4];
#pragma unroll
      for (int i = 0; i < 4; ++i) {
        const int m = wm + i * 16 + fr_row;
        const int slot = (m >> 3) * 64 + (m & 7) * 8 + (c16 ^ (m & 7));
        af[i] = *(const short8*)((const char*)As + slot * 16);
      }
#pragma unroll
      for (int j = 0; j < 4; ++j) {
        const int n = wn + j * 16 + fr_row;
        const int slot = (n >> 3) * 64 + (n & 7) * 8 + (c16 ^ (n & 7));
        bfv[j] = *(const short8*)((const char*)Bs + slot * 16);
      }
#pragma unroll
      for (int i = 0; i < 4; ++i)
#pragma unroll
        for (int j = 0; j < 4; ++j)
          acc[i][j] = __builtin_amdgcn_mfma_f32_16x16x32_bf16(af[i], bfv[j], acc[i][j], 0, 0, 0);
    }
    __syncthreads();
  }

  const int crow = (lane >> 4) * 4;
  const int ccol = lane & 15;
#pragma unroll
  for (int i = 0; i < 4; ++i)
#pragma unroll
    for (int j = 0; j < 4; ++j) {
      const int n = gn0 + wn + j * 16 + ccol;
      const float badd = bias[n];
      const float a0 = (acc[i][j][0] + badd) * oscale;
      const float a1 = (acc[i][j][1] + badd) * oscale;
      const float a2 = (acc[i][j][2] + badd) * oscale;
      const float a3 = (acc[i][j][3] + badd) * oscale;
      const u32 p01 = pk2(a0, a1);
      const u32 p23 = pk2(a2, a3);
      u16* cp = C + (long)(gm0 + wm + i * 16 + crow) * 512 + n;
      cp[0]    = (u16)p01;
      cp[512]  = (u16)(p01 >> 16);
      cp[1024] = (u16)p23;
      cp[1536] = (u16)(p23 >> 16);
    }
}

// ---------------------------------------------------------------- fused K+V projection
// logical x<4 -> K half, x>=4 -> V half (transposed store to Vt).
// XCD-clustered: each XCD = 32 m-panels x all 8 logical x (K+V, 4 n each),
// so the shared ctx A-panel is fetched once per XCD.
__global__ __launch_bounds__(256) void proj_kv(const float* __restrict__ A,
                                               const u16* __restrict__ Wk,
                                               const float* __restrict__ bk,
                                               const u16* __restrict__ Wv,
                                               const float* __restrict__ bv,
                                               u16* __restrict__ Kb,
                                               u16* __restrict__ Vt) {
  __shared__ u16 As[8192];
  __shared__ u16 Bs[8192];
  const int tid = threadIdx.x;
  const int lane = tid & 63;
  const int wave = tid >> 6;
  const int orig = blockIdx.y * 8 + blockIdx.x;      // 0..2047, XCD = orig%8
  const int swz = (orig & 7) * 256 + (orig >> 3);    // bijective chunk swizzle
  const int gm0 = (swz >> 3) * 128;                  // m-panel 0..255
  const int xk = swz & 7;                            // logical x 0..7
  const int isV = xk >> 2;
  const u16* Bt = isV ? Wv : Wk;
  const float* bias = isV ? bv : bk;
  const int gn0 = (xk & 3) * 128;
  const int wm = (wave >> 1) * 64;
  const int wn = (wave & 1) * 64;

  floatx4 acc[4][4];
#pragma unroll
  for (int i = 0; i < 4; ++i)
#pragma unroll
    for (int j = 0; j < 4; ++j)
#pragma unroll
      for (int r = 0; r < 4; ++r) acc[i][j][r] = 0.0f;

  const int lrow = lane >> 3;
  const int lcol = (lane & 7) ^ lrow;
  const int fr_row = lane & 15;
  const int fr_k16 = lane >> 4;

  for (int k0 = 0; k0 < 512; k0 += 64) {
#pragma unroll
    for (int c = 0; c < 4; ++c) {
      const int ch = wave * 4 + c;
      gload16(Bt + (long)(gn0 + ch * 8 + lrow) * 512 + k0 + lcol * 8, (char*)Bs + ch * 1024);
    }
    stage_a_f32(A, 512, gm0, k0, As, tid);
    __syncthreads();
#pragma unroll
    for (int ks = 0; ks < 2; ++ks) {
      const int c16 = ks * 4 + fr_k16;
      short8 af[4], bfv[4];
#pragma unroll
      for (int i = 0; i < 4; ++i) {
        const int m = wm + i * 16 + fr_row;
        const int slot = (m >> 3) * 64 + (m & 7) * 8 + (c16 ^ (m & 7));
        af[i] = *(const short8*)((const char*)As + slot * 16);
      }
#pragma unroll
      for (int j = 0; j < 4; ++j) {
        const int n = wn + j * 16 + fr_row;
        const int slot = (n >> 3) * 64 + (n & 7) * 8 + (c16 ^ (n & 7));
        bfv[j] = *(const short8*)((const char*)Bs + slot * 16);
      }
#pragma unroll
      for (int i = 0; i < 4; ++i)
#pragma unroll
        for (int j = 0; j < 4; ++j)
          acc[i][j] = __builtin_amdgcn_mfma_f32_16x16x32_bf16(af[i], bfv[j], acc[i][j], 0, 0, 0);
    }
    __syncthreads();
  }

  const int crow = (lane >> 4) * 4;
  const int ccol = lane & 15;
  if (!isV) {
#pragma unroll
    for (int i = 0; i < 4; ++i)
#pragma unroll
      for (int j = 0; j < 4; ++j) {
        const int n = gn0 + wn + j * 16 + ccol;
        const float badd = bias[n];
        const u32 p01 = pk2(acc[i][j][0] + badd, acc[i][j][1] + badd);
        const u32 p23 = pk2(acc[i][j][2] + badd, acc[i][j][3] + badd);
        u16* cp = Kb + (long)(gm0 + wm + i * 16 + crow) * 512 + n;
        cp[0]    = (u16)p01;
        cp[512]  = (u16)(p01 >> 16);
        cp[1024] = (u16)p23;
        cp[1536] = (u16)(p23 >> 16);
      }
  } else {
#pragma unroll
    for (int i = 0; i < 4; ++i)
#pragma unroll
      for (int j = 0; j < 4; ++j) {
        const int n = gn0 + wn + j * 16 + ccol;
        const float badd = bias[n];
        const int m = gm0 + wm + i * 16 + crow;  // 4 consecutive m
        const int b = m >> 12;
        const int mm = m & 4095;
        uint2 st;
        st.x = pk2(acc[i][j][0] + badd, acc[i][j][1] + badd);
        st.y = pk2(acc[i][j][2] + badd, acc[i][j][3] + badd);
        *(uint2*)(Vt + (long)b * 512 * 4096 + (long)n * 4096 + mm) = st;
      }
  }
}

// ---------------------------------------------------------------- S-GEMM with fused exp + row-sum stats
// 256x256 tile, 8 waves (512 thr): 64 MFMA per wave-K-step vs 8 staged loads.
// Default block->XCD mapping (R5 evidence: linear %8 keeps K-panels XCD-local).
// Q was pre-scaled by scale*log2(e): S = 2^(Q'K^T) == exp(QK^T*scale).
__global__ __launch_bounds__(512) void gemm_s(
    const u16* __restrict__ A, const u16* __restrict__ Bt, u16* __restrict__ S,
    float* __restrict__ Ld, long aBS, long bBS) {
  __shared__ u16 As[16384];  // 256 x 64 bf16 = 32 KB (32 chunks)
  __shared__ u16 Bs[16384];
  const int tid = threadIdx.x;
  const int lane = tid & 63;
  const int wave = tid >> 6;
  const int bz = blockIdx.z;
  A += (long)bz * aBS;
  Bt += (long)bz * bBS;
  u16* Sb = S + (long)bz * 4096 * 4096;
  const int gm0 = blockIdx.y * 256;
  const int gn0 = blockIdx.x * 256;
  const int wm = (wave >> 2) * 128;   // 2 m-halves
  const int wn = (wave & 3) * 64;     // 4 n-quarters

  floatx4 acc[8][4];
#pragma unroll
  for (int i = 0; i < 8; ++i)
#pragma unroll
    for (int j = 0; j < 4; ++j)
#pragma unroll
      for (int r = 0; r < 4; ++r) acc[i][j][r] = 0.0f;

  const int lrow = lane >> 3;
  const int lcol = (lane & 7) ^ lrow;
  const int fr_row = lane & 15;
  const int fr_k16 = lane >> 4;

  for (int k0 = 0; k0 < 512; k0 += 64) {
#pragma unroll
    for (int c = 0; c < 4; ++c) {
      const int ch = wave * 4 + c;   // 0..31
      const int r = ch * 8 + lrow;   // 0..255
      gload16(A + (long)(gm0 + r) * 512 + k0 + lcol * 8, (char*)As + ch * 1024);
      gload16(Bt + (long)(gn0 + r) * 512 + k0 + lcol * 8, (char*)Bs + ch * 1024);
    }
    __syncthreads();
#pragma unroll
    for (int ks = 0; ks < 2; ++ks) {
      const int c16 = ks * 4 + fr_k16;
      short8 af[8], bfv[4];
#pragma unroll
      for (int i = 0; i < 8; ++i) {
        const int m = wm + i * 16 + fr_row;
        const int slot = (m >> 3) * 64 + (m & 7) * 8 + (c16 ^ (m & 7));
        af[i] = *(const short8*)((const char*)As + slot * 16);
      }
#pragma unroll
      for (int j = 0; j < 4; ++j) {
        const int n = wn + j * 16 + fr_row;
        const int slot = (n >> 3) * 64 + (n & 7) * 8 + (c16 ^ (n & 7));
        bfv[j] = *(const short8*)((const char*)Bs + slot * 16);
      }
#pragma unroll
      for (int i = 0; i < 8; ++i)
#pragma unroll
        for (int j = 0; j < 4; ++j)
          acc[i][j] = __builtin_amdgcn_mfma_f32_16x16x32_bf16(af[i], bfv[j], acc[i][j], 0, 0, 0);
    }
    __syncthreads();
  }

  // epilogue: e = 2^acc; store bf16 (packed cvt); per-row partial sums
  // (4 n-waves per row) -> LDS -> atomicAdd
  const int crow = (lane >> 4) * 4;  // quad*4
  const int ccol = lane & 15;
  float (*sml)[4] = (float (*)[4])As;  // 256 rows x 4 n-waves, aliases dead As
#pragma unroll
  for (int i = 0; i < 8; ++i) {
    float rs0 = 0.f, rs1 = 0.f, rs2 = 0.f, rs3 = 0.f;
    u16* sp = Sb + (long)(gm0 + wm + i * 16 + crow) * 4096 + gn0 + wn + ccol;
#pragma unroll
    for (int j = 0; j < 4; ++j) {
      const float e0 = exp2fast(acc[i][j][0]);
      const float e1 = exp2fast(acc[i][j][1]);
      const float e2 = exp2fast(acc[i][j][2]);
      const float e3 = exp2fast(acc[i][j][3]);
      const u32 p01 = pk2(e0, e1);
      const u32 p23 = pk2(e2, e3);
      u16* q = sp + j * 16;
      q[0]     = (u16)p01;
      q[4096]  = (u16)(p01 >> 16);
      q[8192]  = (u16)p23;
      q[12288] = (u16)(p23 >> 16);
      rs0 += e0; rs1 += e1; rs2 += e2; rs3 += e3;
    }
#pragma unroll
    for (int off = 1; off < 16; off <<= 1) {
      rs0 += __shfl_xor(rs0, off, 64);
      rs1 += __shfl_xor(rs1, off, 64);
      rs2 += __shfl_xor(rs2, off, 64);
      rs3 += __shfl_xor(rs3, off, 64);
    }
    if ((lane & 15) == 0) {
      const int rb = wm + i * 16 + crow;
      sml[rb + 0][wave & 3] = rs0;
      sml[rb + 1][wave & 3] = rs1;
      sml[rb + 2][wave & 3] = rs2;
      sml[rb + 3][wave & 3] = rs3;
    }
  }
  __syncthreads();
  if (tid < 256)
    atomicAdd(&Ld[(long)bz * 4096 + gm0 + tid],
              sml[tid][0] + sml[tid][1] + sml[tid][2] + sml[tid][3]);
}

// ---------------------------------------------------------------- O-GEMM: out = (expS * Vt^T) / l, fp32 out
// 256m x 128n tile, 8 waves (512 thr): 32 MFMA per wave-K-step vs 6 loads
// (2x the 64x128 density); per-WG intensity 45->89 FLOP/B halves logical
// S traffic (384->192 MB/batch). V-centric XCD swizzle: each XCD owns one
// n-block (1 MB V-panel stays L2-hot) x 8 m-panels of streamed S.
__global__ __launch_bounds__(512) void gemm_o(
    const u16* __restrict__ A, const u16* __restrict__ Bt, float* __restrict__ Cout,
    const float* __restrict__ Ld, long aBS, long bBS, long cBS) {
  __shared__ u16 As[16384];  // 256 x 64 bf16 = 32 KB (32 chunks)
  __shared__ u16 Bs[8192];   // 128 x 64 bf16 = 16 KB (16 chunks)
  const int tid = threadIdx.x;
  const int lane = tid & 63;
  const int wave = tid >> 6;
  const int bz = blockIdx.z;
  A += (long)bz * aBS;
  Bt += (long)bz * bBS;
  const long cbase = (long)bz * cBS;
  const int orig = blockIdx.y * 4 + blockIdx.x;  // 0..63
  const int xcd = orig & 7;
  const int seq = orig >> 3;                     // 0..7
  const int gn0 = (xcd >> 1) * 128;              // n-block 0..3 (per-XCD fixed)
  const int gm0 = ((xcd & 1) * 8 + seq) * 256;   // m-panel 0..15
  const int wm = (wave >> 2) * 128;              // 2 m-halves
  const int wn = (wave & 3) * 32;                // 4 n-quarters

  floatx4 acc[8][2];
#pragma unroll
  for (int i = 0; i < 8; ++i)
#pragma unroll
    for (int j = 0; j < 2; ++j)
#pragma unroll
      for (int r = 0; r < 4; ++r) acc[i][j][r] = 0.0f;

  const int lrow = lane >> 3;
  const int lcol = (lane & 7) ^ lrow;
  const int fr_row = lane & 15;
  const int fr_k16 = lane >> 4;

  for (int k0 = 0; k0 < 4096; k0 += 64) {
#pragma unroll
    for (int c = 0; c < 4; ++c) {
      const int ch = wave * 4 + c;   // 0..31
      gload16(A + (long)(gm0 + ch * 8 + lrow) * 4096 + k0 + lcol * 8, (char*)As + ch * 1024);
    }
#pragma unroll
    for (int c = 0; c < 2; ++c) {
      const int ch = wave * 2 + c;   // 0..15
      gload16(Bt + (long)(gn0 + ch * 8 + lrow) * 4096 + k0 + lcol * 8, (char*)Bs + ch * 1024);
    }
    __syncthreads();
#pragma unroll
    for (int ks = 0; ks < 2; ++ks) {
      const int c16 = ks * 4 + fr_k16;
      short8 af[8], bfv[2];
#pragma unroll
      for (int i = 0; i < 8; ++i) {
        const int m = wm + i * 16 + fr_row;
        const int slot = (m >> 3) * 64 + (m & 7) * 8 + (c16 ^ (m & 7));
        af[i] = *(const short8*)((const char*)As + slot * 16);
      }
#pragma unroll
      for (int j = 0; j < 2; ++j) {
        const int n = wn + j * 16 + fr_row;
        const int slot = (n >> 3) * 64 + (n & 7) * 8 + (c16 ^ (n & 7));
        bfv[j] = *(const short8*)((const char*)Bs + slot * 16);
      }
#pragma unroll
      for (int i = 0; i < 8; ++i)
#pragma unroll
        for (int j = 0; j < 2; ++j)
          acc[i][j] = __builtin_amdgcn_mfma_f32_16x16x32_bf16(af[i], bfv[j], acc[i][j], 0, 0, 0);
    }
    __syncthreads();
  }

  const int crow = (lane >> 4) * 4;
  const int ccol = lane & 15;
  float linv[8][4];
#pragma unroll
  for (int i = 0; i < 8; ++i)
#pragma unroll
    for (int r = 0; r < 4; ++r)
      linv[i][r] = 1.0f / Ld[(long)bz * 4096 + gm0 + wm + i * 16 + crow + r];
#pragma unroll
  for (int i = 0; i < 8; ++i)
#pragma unroll
    for (int j = 0; j < 2; ++j) {
      const int n = gn0 + wn + j * 16 + ccol;
#pragma unroll
      for (int r = 0; r < 4; ++r) {
        const int m = gm0 + wm + i * 16 + crow + r;
        Cout[cbase + (long)m * 512 + n] = acc[i][j][r] * linv[i][r];
      }
    }
}

// ---------------------------------------------------------------- host
extern "C" void kernel_launch(void* const* d_in, const int* in_sizes, int n_in,
                              void* d_out, int out_size, void* d_ws, size_t ws_size,
                              hipStream_t stream) {
  const int B = 8, NQ = 4096, NK = 4096, D = 512;
  const long nX = (long)B * NQ * D;
  const long nW = (long)D * D;
  // Q pre-scale: softmax scale * log2(e), so gemm_s can use 2^x directly.
  const float oscale = 0.044194173824159216f * 1.4426950408889634f;

  const float* x = (const float*)d_in[0];
  const float* ctx = (const float*)d_in[1];
  const float* Wq = (const float*)d_in[2];
  const float* bq = (const float*)d_in[3];
  const float* Wk = (const float*)d_in[4];
  const float* bk = (const float*)d_in[5];
  const float* Wv = (const float*)d_in[6];
  const float* bv = (const float*)d_in[7];
  float* out = (float*)d_out;

  // workspace: [Qb][Kb][Vt][Ld] live through attention; weights dead after
  // projections -> S aliases from the weights region onward.
  size_t off = 0;
  auto alloc = [&](size_t bytes) { size_t o = off; off = (off + bytes + 255) & ~(size_t)255; return o; };
  char* ws = (char*)d_ws;
  u16* Qb  = (u16*)(ws + alloc(nX * 2));
  u16* Kb  = (u16*)(ws + alloc(nX * 2));
  u16* Vt  = (u16*)(ws + alloc(nX * 2));
  float* Ld = (float*)(ws + alloc((size_t)B * NQ * 4));  // row sums, 128 KB
  const size_t s_off = off;  // S aliases weights (dead at S time)
  u16* wqb = (u16*)(ws + alloc(nW * 2));
  u16* wkb = (u16*)(ws + alloc(nW * 2));
  u16* wvb = (u16*)(ws + alloc(nW * 2));
  u16* S   = (u16*)(ws + s_off);

  const size_t sBatch = (size_t)NQ * NK * 2;  // 33.5 MB per batch
  const size_t avail = (ws_size > s_off) ? (ws_size - s_off) : 0;
  int nb = (int)(avail / sBatch);
  if (nb > 8) nb = 8;
  else if (nb >= 4 && nb < 8) nb = 4;  // even chunks preferred
  if (nb < 1) nb = 1;

  // 1) weight casts + zero the row-sum array
  cast4_kernel<<<128, 256, 0, stream>>>(Wq, wqb, nW / 4);
  cast4_kernel<<<128, 256, 0, stream>>>(Wk, wkb, nW / 4);
  cast4_kernel<<<128, 256, 0, stream>>>(Wv, wvb, nW / 4);
  zerof<<<(B * NQ / 4 + 255) / 256, 256, 0, stream>>>(Ld, B * NQ / 4);

  // 2) projections with fused fp32->bf16 A-staging
  proj_q<<<dim3(4, 256), 256, 0, stream>>>(x, wqb, bq, Qb, oscale);
  proj_kv<<<dim3(8, 256), 256, 0, stream>>>(ctx, wkb, bk, wvb, bv, Kb, Vt);

  // 3) attention in batch chunks: S-GEMM(+exp+rowsum) then O-GEMM(/l)
  for (int b0 = 0; b0 < B; b0 += nb) {
    const int nbb = (b0 + nb <= B) ? nb : (B - b0);
    gemm_s<<<dim3(16, 16, nbb), 512, 0, stream>>>(
        Qb + (long)b0 * NQ * D, Kb + (long)b0 * NK * D, S,
        Ld + (long)b0 * NQ, (long)NQ * D, (long)NK * D);
    gemm_o<<<dim3(4, 16, nbb), 512, 0, stream>>>(
        S, Vt + (long)b0 * D * NK, out + (long)b0 * NQ * D,
        Ld + (long)b0 * NQ, (long)NQ * NK, (long)D * NK, (long)NQ * D);
  }
  (void)in_sizes; (void)n_in; (void)out_size;
}

// Round 9
// 645.321 us; speedup vs baseline: 1.0933x; 1.0933x over previous
//
#include <hip/hip_runtime.h>
#include <math.h>

typedef unsigned short u16;
typedef unsigned int u32;
typedef __attribute__((ext_vector_type(8))) short short8;   // 8 bf16 = 4 VGPRs
typedef __attribute__((ext_vector_type(4))) float floatx4;  // MFMA 16x16 accumulator

#define DEVINL static __device__ __forceinline__

// pack 2 fp32 -> 2 bf16 (RNE), src0 -> low half, src1 -> high half
DEVINL u32 pk2(float a, float b) {
  u32 r;
  asm("v_cvt_pk_bf16_f32 %0, %1, %2" : "=v"(r) : "v"(a), "v"(b));
  return r;
}
// raw v_exp_f32: returns 2^x
DEVINL float exp2fast(float x) {
  float r;
  asm("v_exp_f32 %0, %1" : "=v"(r) : "v"(x));
  return r;
}

DEVINL void gload16(const void* g, void* lds_base) {
  __builtin_amdgcn_global_load_lds(
      (const __attribute__((address_space(1))) void*)g,
      (__attribute__((address_space(3))) void*)lds_base, 16, 0, 0);
}

// Stage a 128x64 fp32 A-tile into swizzled bf16 LDS chunks (same layout the
// MFMA fragment reader uses). 8 rounds x 256 threads x float4.
DEVINL void stage_a_f32(const float* __restrict__ A, int lda, int gm0, int k0,
                        u16* As, int tid) {
  const int idx = tid & 127;
  const int row8 = idx >> 4;
  const int k16h = idx & 15;
  const int chsel = tid >> 7;
#pragma unroll
  for (int rr = 0; rr < 8; ++rr) {
    const int chunk = rr * 2 + chsel;
    const float4 v = *(const float4*)(A + (long)(gm0 + chunk * 8 + row8) * lda + k0 + k16h * 4);
    const int baddr = chunk * 1024 + row8 * 128 + (((k16h >> 1) ^ row8) << 4) + ((k16h & 1) << 3);
    uint2 p; p.x = pk2(v.x, v.y); p.y = pk2(v.z, v.w);
    *(uint2*)((char*)As + baddr) = p;
  }
}

// ---------------------------------------------------------------- cast fp32->bf16 (weights only)
__global__ __launch_bounds__(256) void cast4_kernel(const float* __restrict__ in,
                                                    u16* __restrict__ out, long n4) {
  long i = (long)blockIdx.x * blockDim.x + threadIdx.x;
  long stride = (long)gridDim.x * blockDim.x;
  for (; i < n4; i += stride) {
    float4 v = ((const float4*)in)[i];
    uint2 o; o.x = pk2(v.x, v.y); o.y = pk2(v.z, v.w);
    ((uint2*)out)[i] = o;
  }
}

// ---------------------------------------------------------------- zero fp32 buffer
__global__ __launch_bounds__(256) void zerof(float* __restrict__ p, int n4) {
  int i = blockIdx.x * 256 + threadIdx.x;
  if (i < n4) ((float4*)p)[i] = make_float4(0.f, 0.f, 0.f, 0.f);
}

// ---------------------------------------------------------------- Q projection
// Stores Q' = (x Wq^T + bq) * oscale, oscale = softmax_scale * log2(e).
// XCD-clustered: each XCD's contiguous block chunk = 32 m-panels x all 4
// n-blocks, so the shared A-panel (256 KB fp32) is reused within one L2.
__global__ __launch_bounds__(256) void proj_q(const float* __restrict__ A,
                                              const u16* __restrict__ Bt,
                                              const float* __restrict__ bias,
                                              u16* __restrict__ C, float oscale) {
  __shared__ u16 As[8192];
  __shared__ u16 Bs[8192];
  const int tid = threadIdx.x;
  const int lane = tid & 63;
  const int wave = tid >> 6;
  const int orig = blockIdx.y * 4 + blockIdx.x;      // 0..1023, XCD = orig%8
  const int swz = (orig & 7) * 128 + (orig >> 3);    // bijective chunk swizzle
  const int gm0 = (swz >> 2) * 128;                  // m-panel 0..255
  const int gn0 = (swz & 3) * 128;                   // n-block 0..3
  const int wm = (wave >> 1) * 64;
  const int wn = (wave & 1) * 64;

  floatx4 acc[4][4];
#pragma unroll
  for (int i = 0; i < 4; ++i)
#pragma unroll
    for (int j = 0; j < 4; ++j)
#pragma unroll
      for (int r = 0; r < 4; ++r) acc[i][j][r] = 0.0f;

  const int lrow = lane >> 3;
  const int lcol = (lane & 7) ^ lrow;
  const int fr_row = lane & 15;
  const int fr_k16 = lane >> 4;

  for (int k0 = 0; k0 < 512; k0 += 64) {
#pragma unroll
    for (int c = 0; c < 4; ++c) {
      const int ch = wave * 4 + c;
      gload16(Bt + (long)(gn0 + ch * 8 + lrow) * 512 + k0 + lcol * 8, (char*)Bs + ch * 1024);
    }
    stage_a_f32(A, 512, gm0, k0, As, tid);
    __syncthreads();
#pragma unroll
    for (int ks = 0; ks < 2; ++ks) {
      const int c16 = ks * 4 + fr_k16;
      short8 af[4], bfv[4];
#pragma unroll
      for (int i = 0; i < 4; ++i) {
        const int m = wm + i * 16 + fr_row;
        const int slot = (m >> 3) * 64 + (m & 7) * 8 + (c16 ^ (m & 7));
        af[i] = *(const short8*)((const char*)As + slot * 16);
      }
#pragma unroll
      for (int j = 0; j < 4; ++j) {
        const int n = wn + j * 16 + fr_row;
        const int slot = (n >> 3) * 64 + (n & 7) * 8 + (c16 ^ (n & 7));
        bfv[j] = *(const short8*)((const char*)Bs + slot * 16);
      }
#pragma unroll
      for (int i = 0; i < 4; ++i)
#pragma unroll
        for (int j = 0; j < 4; ++j)
          acc[i][j] = __builtin_amdgcn_mfma_f32_16x16x32_bf16(af[i], bfv[j], acc[i][j], 0, 0, 0);
    }
    __syncthreads();
  }

  const int crow = (lane >> 4) * 4;
  const int ccol = lane & 15;
#pragma unroll
  for (int i = 0; i < 4; ++i)
#pragma unroll
    for (int j = 0; j < 4; ++j) {
      const int n = gn0 + wn + j * 16 + ccol;
      const float badd = bias[n];
      const float a0 = (acc[i][j][0] + badd) * oscale;
      const float a1 = (acc[i][j][1] + badd) * oscale;
      const float a2 = (acc[i][j][2] + badd) * oscale;
      const float a3 = (acc[i][j][3] + badd) * oscale;
      const u32 p01 = pk2(a0, a1);
      const u32 p23 = pk2(a2, a3);
      u16* cp = C + (long)(gm0 + wm + i * 16 + crow) * 512 + n;
      cp[0]    = (u16)p01;
      cp[512]  = (u16)(p01 >> 16);
      cp[1024] = (u16)p23;
      cp[1536] = (u16)(p23 >> 16);
    }
}

// ---------------------------------------------------------------- fused K+V projection
// logical x<4 -> K half, x>=4 -> V half (transposed store to Vt).
// XCD-clustered: each XCD = 32 m-panels x all 8 logical x (K+V, 4 n each),
// so the shared ctx A-panel is fetched once per XCD.
__global__ __launch_bounds__(256) void proj_kv(const float* __restrict__ A,
                                               const u16* __restrict__ Wk,
                                               const float* __restrict__ bk,
                                               const u16* __restrict__ Wv,
                                               const float* __restrict__ bv,
                                               u16* __restrict__ Kb,
                                               u16* __restrict__ Vt) {
  __shared__ u16 As[8192];
  __shared__ u16 Bs[8192];
  const int tid = threadIdx.x;
  const int lane = tid & 63;
  const int wave = tid >> 6;
  const int orig = blockIdx.y * 8 + blockIdx.x;      // 0..2047, XCD = orig%8
  const int swz = (orig & 7) * 256 + (orig >> 3);    // bijective chunk swizzle
  const int gm0 = (swz >> 3) * 128;                  // m-panel 0..255
  const int xk = swz & 7;                            // logical x 0..7
  const int isV = xk >> 2;
  const u16* Bt = isV ? Wv : Wk;
  const float* bias = isV ? bv : bk;
  const int gn0 = (xk & 3) * 128;
  const int wm = (wave >> 1) * 64;
  const int wn = (wave & 1) * 64;

  floatx4 acc[4][4];
#pragma unroll
  for (int i = 0; i < 4; ++i)
#pragma unroll
    for (int j = 0; j < 4; ++j)
#pragma unroll
      for (int r = 0; r < 4; ++r) acc[i][j][r] = 0.0f;

  const int lrow = lane >> 3;
  const int lcol = (lane & 7) ^ lrow;
  const int fr_row = lane & 15;
  const int fr_k16 = lane >> 4;

  for (int k0 = 0; k0 < 512; k0 += 64) {
#pragma unroll
    for (int c = 0; c < 4; ++c) {
      const int ch = wave * 4 + c;
      gload16(Bt + (long)(gn0 + ch * 8 + lrow) * 512 + k0 + lcol * 8, (char*)Bs + ch * 1024);
    }
    stage_a_f32(A, 512, gm0, k0, As, tid);
    __syncthreads();
#pragma unroll
    for (int ks = 0; ks < 2; ++ks) {
      const int c16 = ks * 4 + fr_k16;
      short8 af[4], bfv[4];
#pragma unroll
      for (int i = 0; i < 4; ++i) {
        const int m = wm + i * 16 + fr_row;
        const int slot = (m >> 3) * 64 + (m & 7) * 8 + (c16 ^ (m & 7));
        af[i] = *(const short8*)((const char*)As + slot * 16);
      }
#pragma unroll
      for (int j = 0; j < 4; ++j) {
        const int n = wn + j * 16 + fr_row;
        const int slot = (n >> 3) * 64 + (n & 7) * 8 + (c16 ^ (n & 7));
        bfv[j] = *(const short8*)((const char*)Bs + slot * 16);
      }
#pragma unroll
      for (int i = 0; i < 4; ++i)
#pragma unroll
        for (int j = 0; j < 4; ++j)
          acc[i][j] = __builtin_amdgcn_mfma_f32_16x16x32_bf16(af[i], bfv[j], acc[i][j], 0, 0, 0);
    }
    __syncthreads();
  }

  const int crow = (lane >> 4) * 4;
  const int ccol = lane & 15;
  if (!isV) {
#pragma unroll
    for (int i = 0; i < 4; ++i)
#pragma unroll
      for (int j = 0; j < 4; ++j) {
        const int n = gn0 + wn + j * 16 + ccol;
        const float badd = bias[n];
        const u32 p01 = pk2(acc[i][j][0] + badd, acc[i][j][1] + badd);
        const u32 p23 = pk2(acc[i][j][2] + badd, acc[i][j][3] + badd);
        u16* cp = Kb + (long)(gm0 + wm + i * 16 + crow) * 512 + n;
        cp[0]    = (u16)p01;
        cp[512]  = (u16)(p01 >> 16);
        cp[1024] = (u16)p23;
        cp[1536] = (u16)(p23 >> 16);
      }
  } else {
#pragma unroll
    for (int i = 0; i < 4; ++i)
#pragma unroll
      for (int j = 0; j < 4; ++j) {
        const int n = gn0 + wn + j * 16 + ccol;
        const float badd = bias[n];
        const int m = gm0 + wm + i * 16 + crow;  // 4 consecutive m
        const int b = m >> 12;
        const int mm = m & 4095;
        uint2 st;
        st.x = pk2(acc[i][j][0] + badd, acc[i][j][1] + badd);
        st.y = pk2(acc[i][j][2] + badd, acc[i][j][3] + badd);
        *(uint2*)(Vt + (long)b * 512 * 4096 + (long)n * 4096 + mm) = st;
      }
  }
}

// ---------------------------------------------------------------- S-GEMM with fused exp + row-sum stats
// 256x256 tile, 8 waves (512 thr): 64 MFMA per wave-K-step vs 8 staged loads.
// Default block->XCD mapping (R5 evidence: linear %8 keeps K-panels XCD-local).
// Q was pre-scaled by scale*log2(e): S = 2^(Q'K^T) == exp(QK^T*scale).
__global__ __launch_bounds__(512) void gemm_s(
    const u16* __restrict__ A, const u16* __restrict__ Bt, u16* __restrict__ S,
    float* __restrict__ Ld, long aBS, long bBS) {
  __shared__ u16 As[16384];  // 256 x 64 bf16 = 32 KB (32 chunks)
  __shared__ u16 Bs[16384];
  const int tid = threadIdx.x;
  const int lane = tid & 63;
  const int wave = tid >> 6;
  const int bz = blockIdx.z;
  A += (long)bz * aBS;
  Bt += (long)bz * bBS;
  u16* Sb = S + (long)bz * 4096 * 4096;
  const int gm0 = blockIdx.y * 256;
  const int gn0 = blockIdx.x * 256;
  const int wm = (wave >> 2) * 128;   // 2 m-halves
  const int wn = (wave & 3) * 64;     // 4 n-quarters

  floatx4 acc[8][4];
#pragma unroll
  for (int i = 0; i < 8; ++i)
#pragma unroll
    for (int j = 0; j < 4; ++j)
#pragma unroll
      for (int r = 0; r < 4; ++r) acc[i][j][r] = 0.0f;

  const int lrow = lane >> 3;
  const int lcol = (lane & 7) ^ lrow;
  const int fr_row = lane & 15;
  const int fr_k16 = lane >> 4;

  for (int k0 = 0; k0 < 512; k0 += 64) {
#pragma unroll
    for (int c = 0; c < 4; ++c) {
      const int ch = wave * 4 + c;   // 0..31
      const int r = ch * 8 + lrow;   // 0..255
      gload16(A + (long)(gm0 + r) * 512 + k0 + lcol * 8, (char*)As + ch * 1024);
      gload16(Bt + (long)(gn0 + r) * 512 + k0 + lcol * 8, (char*)Bs + ch * 1024);
    }
    __syncthreads();
#pragma unroll
    for (int ks = 0; ks < 2; ++ks) {
      const int c16 = ks * 4 + fr_k16;
      short8 af[8], bfv[4];
#pragma unroll
      for (int i = 0; i < 8; ++i) {
        const int m = wm + i * 16 + fr_row;
        const int slot = (m >> 3) * 64 + (m & 7) * 8 + (c16 ^ (m & 7));
        af[i] = *(const short8*)((const char*)As + slot * 16);
      }
#pragma unroll
      for (int j = 0; j < 4; ++j) {
        const int n = wn + j * 16 + fr_row;
        const int slot = (n >> 3) * 64 + (n & 7) * 8 + (c16 ^ (n & 7));
        bfv[j] = *(const short8*)((const char*)Bs + slot * 16);
      }
#pragma unroll
      for (int i = 0; i < 8; ++i)
#pragma unroll
        for (int j = 0; j < 4; ++j)
          acc[i][j] = __builtin_amdgcn_mfma_f32_16x16x32_bf16(af[i], bfv[j], acc[i][j], 0, 0, 0);
    }
    __syncthreads();
  }

  // epilogue: e = 2^acc; store bf16 (packed cvt); per-row partial sums
  // (4 n-waves per row) -> LDS -> atomicAdd
  const int crow = (lane >> 4) * 4;  // quad*4
  const int ccol = lane & 15;
  float (*sml)[4] = (float (*)[4])As;  // 256 rows x 4 n-waves, aliases dead As
#pragma unroll
  for (int i = 0; i < 8; ++i) {
    float rs0 = 0.f, rs1 = 0.f, rs2 = 0.f, rs3 = 0.f;
    u16* sp = Sb + (long)(gm0 + wm + i * 16 + crow) * 4096 + gn0 + wn + ccol;
#pragma unroll
    for (int j = 0; j < 4; ++j) {
      const float e0 = exp2fast(acc[i][j][0]);
      const float e1 = exp2fast(acc[i][j][1]);
      const float e2 = exp2fast(acc[i][j][2]);
      const float e3 = exp2fast(acc[i][j][3]);
      const u32 p01 = pk2(e0, e1);
      const u32 p23 = pk2(e2, e3);
      u16* q = sp + j * 16;
      q[0]     = (u16)p01;
      q[4096]  = (u16)(p01 >> 16);
      q[8192]  = (u16)p23;
      q[12288] = (u16)(p23 >> 16);
      rs0 += e0; rs1 += e1; rs2 += e2; rs3 += e3;
    }
#pragma unroll
    for (int off = 1; off < 16; off <<= 1) {
      rs0 += __shfl_xor(rs0, off, 64);
      rs1 += __shfl_xor(rs1, off, 64);
      rs2 += __shfl_xor(rs2, off, 64);
      rs3 += __shfl_xor(rs3, off, 64);
    }
    if ((lane & 15) == 0) {
      const int rb = wm + i * 16 + crow;
      sml[rb + 0][wave & 3] = rs0;
      sml[rb + 1][wave & 3] = rs1;
      sml[rb + 2][wave & 3] = rs2;
      sml[rb + 3][wave & 3] = rs3;
    }
  }
  __syncthreads();
  if (tid < 256)
    atomicAdd(&Ld[(long)bz * 4096 + gm0 + tid],
              sml[tid][0] + sml[tid][1] + sml[tid][2] + sml[tid][3]);
}

// ---------------------------------------------------------------- O-GEMM: out = (expS * Vt^T) / l, fp32 out
// R6 shape restored (64m x 128n, 4 waves, grid 1024 -> 2-3 WG/CU).
// Batch->XCD clustering: with nbb in {1,2,4,8}, g = 8/nbb XCDs serve each
// batch exclusively -> each XCD's V slice (<=4 MB) is L2-resident for its
// whole lifetime, and each S-panel's 4 n-blocks are adjacent on one XCD
// (S fetched once). R7's FETCH=278 MB (S x4 across XCDs) -> ~170 MB.
__global__ __launch_bounds__(256) void gemm_o(
    const u16* __restrict__ A, const u16* __restrict__ Bt, float* __restrict__ Cout,
    const float* __restrict__ Ld, long aBS, long bBS, long cBS, int nbb) {
  __shared__ u16 As[4096];   // 64 x 64 bf16 = 8 KB (8 chunks)
  __shared__ u16 Bs[8192];   // 128 x 64 bf16 = 16 KB (16 chunks)
  const int tid = threadIdx.x;
  const int lane = tid & 63;
  const int wave = tid >> 6;
  // flat hardware block id (x fastest); XCD = flat % 8 on MI355X dispatch.
  const int flat = (blockIdx.z * 64 + blockIdx.y) * 4 + blockIdx.x;
  const int xcd = flat & 7;
  const int s = flat >> 3;                  // per-XCD sequence, 0..32*nbb-1
  const int g = 8 / nbb;                    // XCDs per batch
  const int bz = xcd / g;                   // this XCD's exclusive batch
  const int work = (xcd % g) * (32 * nbb) + s;  // 0..255 within batch
  const int gm0 = (work >> 2) * 64;         // m-panel 0..63 (4 n's adjacent)
  const int gn0 = (work & 3) * 128;         // n-block 0..3
  A += (long)bz * aBS;
  Bt += (long)bz * bBS;
  const long cbase = (long)bz * cBS;
  const int wn = wave * 32;  // each wave: full 64 m x 32 n slice

  floatx4 acc[4][2];
#pragma unroll
  for (int i = 0; i < 4; ++i)
#pragma unroll
    for (int j = 0; j < 2; ++j)
#pragma unroll
      for (int r = 0; r < 4; ++r) acc[i][j][r] = 0.0f;

  const int lrow = lane >> 3;
  const int lcol = (lane & 7) ^ lrow;
  const int fr_row = lane & 15;
  const int fr_k16 = lane >> 4;

  for (int k0 = 0; k0 < 4096; k0 += 64) {
#pragma unroll
    for (int c = 0; c < 2; ++c) {
      const int ch = wave * 2 + c;
      gload16(A + (long)(gm0 + ch * 8 + lrow) * 4096 + k0 + lcol * 8, (char*)As + ch * 1024);
    }
#pragma unroll
    for (int c = 0; c < 4; ++c) {
      const int ch = wave * 4 + c;
      gload16(Bt + (long)(gn0 + ch * 8 + lrow) * 4096 + k0 + lcol * 8, (char*)Bs + ch * 1024);
    }
    __syncthreads();
#pragma unroll
    for (int ks = 0; ks < 2; ++ks) {
      const int c16 = ks * 4 + fr_k16;
      short8 af[4], bfv[2];
#pragma unroll
      for (int i = 0; i < 4; ++i) {
        const int m = i * 16 + fr_row;
        const int slot = (m >> 3) * 64 + (m & 7) * 8 + (c16 ^ (m & 7));
        af[i] = *(const short8*)((const char*)As + slot * 16);
      }
#pragma unroll
      for (int j = 0; j < 2; ++j) {
        const int n = wn + j * 16 + fr_row;
        const int slot = (n >> 3) * 64 + (n & 7) * 8 + (c16 ^ (n & 7));
        bfv[j] = *(const short8*)((const char*)Bs + slot * 16);
      }
#pragma unroll
      for (int i = 0; i < 4; ++i)
#pragma unroll
        for (int j = 0; j < 2; ++j)
          acc[i][j] = __builtin_amdgcn_mfma_f32_16x16x32_bf16(af[i], bfv[j], acc[i][j], 0, 0, 0);
    }
    __syncthreads();
  }

  const int crow = (lane >> 4) * 4;
  const int ccol = lane & 15;
  float linv[4][4];
#pragma unroll
  for (int i = 0; i < 4; ++i)
#pragma unroll
    for (int r = 0; r < 4; ++r)
      linv[i][r] = 1.0f / Ld[(long)bz * 4096 + gm0 + i * 16 + crow + r];
#pragma unroll
  for (int i = 0; i < 4; ++i)
#pragma unroll
    for (int j = 0; j < 2; ++j) {
      const int n = gn0 + wn + j * 16 + ccol;
#pragma unroll
      for (int r = 0; r < 4; ++r) {
        const int m = gm0 + i * 16 + crow + r;
        Cout[cbase + (long)m * 512 + n] = acc[i][j][r] * linv[i][r];
      }
    }
}

// ---------------------------------------------------------------- host
extern "C" void kernel_launch(void* const* d_in, const int* in_sizes, int n_in,
                              void* d_out, int out_size, void* d_ws, size_t ws_size,
                              hipStream_t stream) {
  const int B = 8, NQ = 4096, NK = 4096, D = 512;
  const long nX = (long)B * NQ * D;
  const long nW = (long)D * D;
  // Q pre-scale: softmax scale * log2(e), so gemm_s can use 2^x directly.
  const float oscale = 0.044194173824159216f * 1.4426950408889634f;

  const float* x = (const float*)d_in[0];
  const float* ctx = (const float*)d_in[1];
  const float* Wq = (const float*)d_in[2];
  const float* bq = (const float*)d_in[3];
  const float* Wk = (const float*)d_in[4];
  const float* bk = (const float*)d_in[5];
  const float* Wv = (const float*)d_in[6];
  const float* bv = (const float*)d_in[7];
  float* out = (float*)d_out;

  // workspace: [Qb][Kb][Vt][Ld] live through attention; weights dead after
  // projections -> S aliases from the weights region onward.
  size_t off = 0;
  auto alloc = [&](size_t bytes) { size_t o = off; off = (off + bytes + 255) & ~(size_t)255; return o; };
  char* ws = (char*)d_ws;
  u16* Qb  = (u16*)(ws + alloc(nX * 2));
  u16* Kb  = (u16*)(ws + alloc(nX * 2));
  u16* Vt  = (u16*)(ws + alloc(nX * 2));
  float* Ld = (float*)(ws + alloc((size_t)B * NQ * 4));  // row sums, 128 KB
  const size_t s_off = off;  // S aliases weights (dead at S time)
  u16* wqb = (u16*)(ws + alloc(nW * 2));
  u16* wkb = (u16*)(ws + alloc(nW * 2));
  u16* wvb = (u16*)(ws + alloc(nW * 2));
  u16* S   = (u16*)(ws + s_off);

  const size_t sBatch = (size_t)NQ * NK * 2;  // 33.5 MB per batch
  const size_t avail = (ws_size > s_off) ? (ws_size - s_off) : 0;
  int nb = (int)(avail / sBatch);
  // power-of-2 chunks so 8 % nb == 0 (batch->XCD clustering in gemm_o)
  if (nb >= 8) nb = 8;
  else if (nb >= 4) nb = 4;
  else if (nb >= 2) nb = 2;
  else nb = 1;

  // 1) weight casts + zero the row-sum array
  cast4_kernel<<<128, 256, 0, stream>>>(Wq, wqb, nW / 4);
  cast4_kernel<<<128, 256, 0, stream>>>(Wk, wkb, nW / 4);
  cast4_kernel<<<128, 256, 0, stream>>>(Wv, wvb, nW / 4);
  zerof<<<(B * NQ / 4 + 255) / 256, 256, 0, stream>>>(Ld, B * NQ / 4);

  // 2) projections with fused fp32->bf16 A-staging
  proj_q<<<dim3(4, 256), 256, 0, stream>>>(x, wqb, bq, Qb, oscale);
  proj_kv<<<dim3(8, 256), 256, 0, stream>>>(ctx, wkb, bk, wvb, bv, Kb, Vt);

  // 3) attention in batch chunks: S-GEMM(+exp+rowsum) then O-GEMM(/l)
  for (int b0 = 0; b0 < B; b0 += nb) {
    const int nbb = (b0 + nb <= B) ? nb : (B - b0);
    gemm_s<<<dim3(16, 16, nbb), 512, 0, stream>>>(
        Qb + (long)b0 * NQ * D, Kb + (long)b0 * NK * D, S,
        Ld + (long)b0 * NQ, (long)NQ * D, (long)NK * D);
    gemm_o<<<dim3(4, 64, nbb), 256, 0, stream>>>(
        S, Vt + (long)b0 * D * NK, out + (long)b0 * NQ * D,
        Ld + (long)b0 * NQ, (long)NQ * NK, (long)D * NK, (long)NQ * D, nbb);
  }
  (void)in_sizes; (void)n_in; (void)out_size;
}